// Round 1
// 455.726 us; speedup vs baseline: 1.0579x; 1.0579x over previous
//
#include <hip/hip_runtime.h>

// Problem dims
#define T_LEN 8192
#define H_DIM 2048
#define K_DIM 512
#define V_DIM 512
#define O_DIM 2048
#define CHUNK 64
#define NCHUNK 128   // T_LEN / CHUNK
#define CGROUP 64    // chunks per scan/intra pass (2 passes)

typedef short bf16x8 __attribute__((ext_vector_type(8)));
typedef float f32x4 __attribute__((ext_vector_type(4)));

typedef const __attribute__((address_space(1))) void* gptr1_t;
typedef __attribute__((address_space(3))) void* lptr3_t;

__device__ __forceinline__ float b2f(unsigned short u) {
    unsigned int i = ((unsigned int)u) << 16;
    float f;
    __builtin_memcpy(&f, &i, 4);
    return f;
}
__device__ __forceinline__ unsigned short f2b(float f) {
    unsigned int i;
    __builtin_memcpy(&i, &f, 4);
    unsigned int r = (i + 0x7FFFu + ((i >> 16) & 1u)) >> 16;  // RNE
    return (unsigned short)r;
}
// NaN/inf firewall
__device__ __forceinline__ float fw(float v) {
    return fminf(fmaxf(v, -1e30f), 1e30f);
}

// ---------------------------------------------------------------------------
// fp32 -> bf16 pack, 8 elements/thread. N multiple of 8.
__global__ __launch_bounds__(256) void conv2bf_k(const float* __restrict__ in,
                                                 unsigned short* __restrict__ out,
                                                 long N) {
    long i = ((long)blockIdx.x * 256 + threadIdx.x) * 8;
    if (i >= N) return;
    unsigned int w[4];
#pragma unroll
    for (int u = 0; u < 4; u++) {
        unsigned short lo = f2b(in[i + 2 * u]);
        unsigned short hi = f2b(in[i + 2 * u + 1]);
        w[u] = (unsigned int)lo | ((unsigned int)hi << 16);
    }
    uint4 pk; pk.x = w[0]; pk.y = w[1]; pk.z = w[2]; pk.w = w[3];
    *(uint4*)(out + i) = pk;
}

// ---------------------------------------------------------------------------
// Runtime C/D-layout probe for mfma_f32_16x16x32_bf16 (vs our load convention).
__global__ __launch_bounds__(64) void probe_k(int* __restrict__ flag) {
    __shared__ unsigned short As[16 * 32];
    __shared__ unsigned short Bs[16 * 32];
    int tid = threadIdx.x;
    for (int idx = tid; idx < 512; idx += 64) {
        int r = idx >> 5, c = idx & 31;
        float av = (c == 0) ? (float)(r + 1) : (c == 1 ? 1.0f : 0.0f);
        float bv = (c == 0) ? 1.0f : (c == 1 ? (float)(1024 * (r + 1)) : 0.0f);
        As[r * 32 + c] = f2b(av);
        Bs[r * 32 + c] = f2b(bv);
    }
    __syncthreads();
    int ln15 = tid & 15, q4 = (tid & 63) >> 4;
    bf16x8 a = *(const bf16x8*)(As + ln15 * 32 + q4 * 8);
    bf16x8 b = *(const bf16x8*)(Bs + ln15 * 32 + q4 * 8);
    f32x4 acc = {0.f, 0.f, 0.f, 0.f};
    acc = __builtin_amdgcn_mfma_f32_16x16x32_bf16(a, b, acc, 0, 0, 0);
    bool h0 = true, h1 = true;
#pragma unroll
    for (int i = 0; i < 4; i++) {
        float e0 = (float)((q4 * 4 + i + 1) + 1024 * (ln15 + 1));
        float e1 = (float)((ln15 + 1) + 1024 * (q4 * 4 + i + 1));
        h0 = h0 && (acc[i] == e0);
        h1 = h1 && (acc[i] == e1);
    }
    unsigned long long b0 = __ballot(h0 ? 1 : 0);
    unsigned long long b1 = __ballot(h1 ? 1 : 0);
    if (tid == 0) *flag = (b0 == ~0ull) ? 0 : ((b1 == ~0ull) ? 1 : 0);
}

// ---------------------------------------------------------------------------
// Transpose to bf16: in[R][C] -> out[C][R]. DF=1: in fp32; DF=0: bf16.
template <int DF>
__global__ __launch_bounds__(256) void transpose_k(const void* __restrict__ in,
                                                   unsigned short* __restrict__ out,
                                                   int R, int C) {
    __shared__ unsigned short tile[32][33];
    int br = blockIdx.x, bc = blockIdx.y;
    int tc = threadIdx.x & 31, tr = threadIdx.x >> 5;
#pragma unroll
    for (int i = 0; i < 4; i++) {
        int r = tr + 8 * i;
        long idx = (long)(br * 32 + r) * C + bc * 32 + tc;
        tile[r][tc] = DF ? f2b(((const float*)in)[idx]) : ((const unsigned short*)in)[idx];
    }
    __syncthreads();
#pragma unroll
    for (int i = 0; i < 4; i++) {
        int r = tr + 8 * i;
        out[(long)(bc * 32 + r) * R + br * 32 + tc] = tile[tc][r];
    }
}

// ---------------------------------------------------------------------------
// Fused projection GEMM, 256x256 8-phase structure (m201 template, T2+T3+T4+T5).
// A=[T][H] bf16, WT=[2048][H] bf16 (rows: q512|k512|g512|v512). grid (32, 8),
// 512 threads (8 waves = 2M x 4N), BK=64, 128 KiB LDS (2 dbuf x 2 halves x A,B).
//
// Per K-tile: 4 phases, one C-quadrant (16 MFMA) each:
//   r0 (m-lo,n-lo): ds_read a-lo(8)+b-lo(4); stage B-hi(t+1)
//   r1 (m-lo,n-hi): ds_read b-hi(4);         stage A-hi(t+1)
//   r2 (m-hi,n-hi): ds_read a-hi(8);         stage A-lo(t+2) -> CURRENT buf (slot
//                                            last ds_read in r0, barrier since)
//   r3 (m-hi,n-lo): no ds_read (regs);       stage B-lo(t+2) -> current buf
// Each phase: [ds_reads; stage-issue; s_barrier; lgkmcnt(0)+sched_barrier(0);
//             setprio(1); 16 MFMA; setprio(0); s_barrier]
// vmcnt(4) ONCE per tile at r3 (before trailing barrier): outstanding=12 loads,
// retires exactly tile t+1's 4 half-tiles, leaves 2 half-tiles (4 loads) in
// flight. Never drains to 0 in the loop. Tail stages wrap (kt mod H) into
// never-read slots so the count schedule stays uniform.
//
// T2 swizzle: 16B-slot XOR  slot ^= (ldsrow & 7)  applied on the pre-swizzled
// GLOBAL source (linear global_load_lds dest) and identically on ds_read_b128
// addresses -> 2 lanes/bank (free) instead of 16-way conflicts.
__global__ __launch_bounds__(512, 2) void proj_gemm256_k(const unsigned short* __restrict__ A,
                                                         const unsigned short* __restrict__ WT,
                                                         const float* __restrict__ bq,
                                                         const float* __restrict__ bk,
                                                         const float* __restrict__ bg,
                                                         const float* __restrict__ bv,
                                                         unsigned short* __restrict__ qb,
                                                         unsigned short* __restrict__ kb,
                                                         float* __restrict__ gb,
                                                         unsigned short* __restrict__ vT,
                                                         const int* __restrict__ flagp) {
    __shared__ unsigned short As[2][256 * 64];  // 64 KiB (row-ordered: half|sub|local)
    __shared__ unsigned short Bs[2][256 * 64];  // 64 KiB
    int fl = *flagp;
    int tid = threadIdx.x;
    int lane = tid & 63;
    int ln15 = lane & 15, q4 = lane >> 4;
    int w = tid >> 6;
    int wm = w >> 2, wn = w & 3;  // 2 x 4 wave grid; wave owns 128 rows x 64 cols
    long m0 = (long)blockIdx.x * 256, n0 = (long)blockIdx.y * 256;

    // ---- staging geometry (per thread, 2 loads per half-tile) ----
    // half-tile = 128 lds-rows x 64 cols bf16 = 16 KiB, linear dest.
    // lds row r holds global row: A: trow = ((r>>6)&1)*128 + half*64 + (r&63)
    //                             B: tcol = ((r>>5)&3)*64  + half*32 + (r&31)
    // stored col16-slot s holds logical slot s ^ (r&7)  (T2 involution).
    int idx0 = tid, idx1 = 512 + tid;
    int r0_ = idx0 >> 3, r1_ = idx1 >> 3;          // lds row within half (0..127)
    int c80 = (idx0 & 7) ^ (r0_ & 7);              // source col16 (units of 8 bf16)
    int c81 = (idx1 & 7) ^ (r1_ & 7);
    int trA0 = ((r0_ >> 6) & 1) * 128 + (r0_ & 63);
    int trA1 = ((r1_ >> 6) & 1) * 128 + (r1_ & 63);
    int tcB0 = ((r0_ >> 5) & 3) * 64 + (r0_ & 31);
    int tcB1 = ((r1_ >> 5) & 3) * 64 + (r1_ & 31);
    const unsigned short* gA0 = A + (m0 + trA0) * (long)H_DIM + c80 * 8;
    const unsigned short* gA1 = A + (m0 + trA1) * (long)H_DIM + c81 * 8;
    const unsigned short* gB0 = WT + (n0 + tcB0) * (long)H_DIM + c80 * 8;
    const unsigned short* gB1 = WT + (n0 + tcB1) * (long)H_DIM + c81 * 8;
    int ld0 = idx0 * 8, ld1 = idx1 * 8;  // lds offset in shorts (16B per thread-load)

#define STAGE_A(buf, half, ks)                                                              \
    do {                                                                                    \
        __builtin_amdgcn_global_load_lds(                                                   \
            (gptr1_t)(const void*)(gA0 + (long)(half) * 64 * H_DIM + (ks)),                 \
            (lptr3_t)(void*)(&As[buf][(half) * 8192 + ld0]), 16, 0, 0);                     \
        __builtin_amdgcn_global_load_lds(                                                   \
            (gptr1_t)(const void*)(gA1 + (long)(half) * 64 * H_DIM + (ks)),                 \
            (lptr3_t)(void*)(&As[buf][(half) * 8192 + ld1]), 16, 0, 0);                     \
    } while (0)
#define STAGE_B(buf, half, ks)                                                              \
    do {                                                                                    \
        __builtin_amdgcn_global_load_lds(                                                   \
            (gptr1_t)(const void*)(gB0 + (long)(half) * 32 * H_DIM + (ks)),                 \
            (lptr3_t)(void*)(&Bs[buf][(half) * 8192 + ld0]), 16, 0, 0);                     \
        __builtin_amdgcn_global_load_lds(                                                   \
            (gptr1_t)(const void*)(gB1 + (long)(half) * 32 * H_DIM + (ks)),                 \
            (lptr3_t)(void*)(&Bs[buf][(half) * 8192 + ld1]), 16, 0, 0);                     \
    } while (0)

    // ---- swizzled fragment reads (ds_read_b128) ----
    auto LDA = [&](int buf, int im, int s) -> bf16x8 {
        int row = (im >> 2) * 128 + wm * 64 + (im & 3) * 16 + ln15;
        int cb = (s * 64 + q4 * 16) ^ ((row & 7) << 4);
        return *(const bf16x8*)((const unsigned short*)As[buf] + row * 64 + (cb >> 1));
    };
    auto LDB = [&](int buf, int jn, int s) -> bf16x8 {
        int row = (jn >> 1) * 128 + wn * 32 + (jn & 1) * 16 + ln15;
        int cb = (s * 64 + q4 * 16) ^ ((row & 7) << 4);
        return *(const bf16x8*)((const unsigned short*)Bs[buf] + row * 64 + (cb >> 1));
    };

    f32x4 acc[8][4] = {};

    // ---- prologue: tile0 full -> buf0, tile1 lo-halves -> buf1 ----
    STAGE_A(0, 0, 0);
    STAGE_B(0, 0, 0);
    STAGE_B(0, 1, 0);
    STAGE_A(0, 1, 0);
    STAGE_A(1, 0, 64);
    STAGE_B(1, 0, 64);
    asm volatile("s_waitcnt vmcnt(4)" ::: "memory");  // tile0 landed, 2 half-tiles in flight
    __builtin_amdgcn_s_barrier();

    int cur = 0;
    for (int kt = 0; kt < H_DIM; kt += 64, cur ^= 1) {
        int k1 = (kt + 64) & (H_DIM - 1);    // tile t+1 source col (wraps to dummy at tail)
        int k2 = (kt + 128) & (H_DIM - 1);   // tile t+2 source col
        bf16x8 af[4][2], blo[2][2], bhi[2][2];

        // ---------------- phase r0: quadrant (m-lo, n-lo) ----------------
#pragma unroll
        for (int i = 0; i < 4; i++) { af[i][0] = LDA(cur, i, 0); af[i][1] = LDA(cur, i, 1); }
#pragma unroll
        for (int j = 0; j < 2; j++) { blo[j][0] = LDB(cur, j, 0); blo[j][1] = LDB(cur, j, 1); }
        STAGE_B(cur ^ 1, 1, k1);
        __builtin_amdgcn_s_barrier();
        asm volatile("s_waitcnt lgkmcnt(0)" ::: "memory");
        __builtin_amdgcn_sched_barrier(0);
        __builtin_amdgcn_s_setprio(1);
#pragma unroll
        for (int i = 0; i < 4; i++)
#pragma unroll
            for (int j = 0; j < 2; j++) {
                acc[i][j] = __builtin_amdgcn_mfma_f32_16x16x32_bf16(af[i][0], blo[j][0], acc[i][j], 0, 0, 0);
                acc[i][j] = __builtin_amdgcn_mfma_f32_16x16x32_bf16(af[i][1], blo[j][1], acc[i][j], 0, 0, 0);
            }
        __builtin_amdgcn_s_setprio(0);
        __builtin_amdgcn_s_barrier();

        // ---------------- phase r1: quadrant (m-lo, n-hi) ----------------
#pragma unroll
        for (int j = 0; j < 2; j++) { bhi[j][0] = LDB(cur, 2 + j, 0); bhi[j][1] = LDB(cur, 2 + j, 1); }
        STAGE_A(cur ^ 1, 1, k1);
        __builtin_amdgcn_s_barrier();
        asm volatile("s_waitcnt lgkmcnt(0)" ::: "memory");
        __builtin_amdgcn_sched_barrier(0);
        __builtin_amdgcn_s_setprio(1);
#pragma unroll
        for (int i = 0; i < 4; i++)
#pragma unroll
            for (int j = 0; j < 2; j++) {
                acc[i][2 + j] = __builtin_amdgcn_mfma_f32_16x16x32_bf16(af[i][0], bhi[j][0], acc[i][2 + j], 0, 0, 0);
                acc[i][2 + j] = __builtin_amdgcn_mfma_f32_16x16x32_bf16(af[i][1], bhi[j][1], acc[i][2 + j], 0, 0, 0);
            }
        __builtin_amdgcn_s_setprio(0);
        __builtin_amdgcn_s_barrier();

        // ---------------- phase r2: quadrant (m-hi, n-hi) ----------------
#pragma unroll
        for (int i = 0; i < 4; i++) { af[i][0] = LDA(cur, 4 + i, 0); af[i][1] = LDA(cur, 4 + i, 1); }
        STAGE_A(cur, 0, k2);  // A-lo(cur): last ds_read in r0, safe to overwrite
        __builtin_amdgcn_s_barrier();
        asm volatile("s_waitcnt lgkmcnt(0)" ::: "memory");
        __builtin_amdgcn_sched_barrier(0);
        __builtin_amdgcn_s_setprio(1);
#pragma unroll
        for (int i = 0; i < 4; i++)
#pragma unroll
            for (int j = 0; j < 2; j++) {
                acc[4 + i][2 + j] = __builtin_amdgcn_mfma_f32_16x16x32_bf16(af[i][0], bhi[j][0], acc[4 + i][2 + j], 0, 0, 0);
                acc[4 + i][2 + j] = __builtin_amdgcn_mfma_f32_16x16x32_bf16(af[i][1], bhi[j][1], acc[4 + i][2 + j], 0, 0, 0);
            }
        __builtin_amdgcn_s_setprio(0);
        __builtin_amdgcn_s_barrier();

        // ---------------- phase r3: quadrant (m-hi, n-lo), regs only ----------------
        STAGE_B(cur, 0, k2);  // B-lo(cur): last ds_read in r0, safe
        __builtin_amdgcn_s_setprio(1);
#pragma unroll
        for (int i = 0; i < 4; i++)
#pragma unroll
            for (int j = 0; j < 2; j++) {
                acc[4 + i][j] = __builtin_amdgcn_mfma_f32_16x16x32_bf16(af[i][0], blo[j][0], acc[4 + i][j], 0, 0, 0);
                acc[4 + i][j] = __builtin_amdgcn_mfma_f32_16x16x32_bf16(af[i][1], blo[j][1], acc[4 + i][j], 0, 0, 0);
            }
        __builtin_amdgcn_s_setprio(0);
        // counted wait: retires tile t+1's 4 half-tiles, keeps t+2's lo pair in flight
        asm volatile("s_waitcnt vmcnt(4)" ::: "memory");
        __builtin_amdgcn_s_barrier();
    }

    // ---- epilogue: segment-dependent writes ----
    int seg = (int)(n0 >> 9);        // 0=q 1=k 2=g 3=v  (256-tile never crosses 512 seg)
    int nl0 = (int)(n0 & 511);
    const float* bias = seg == 0 ? bq : seg == 1 ? bk : seg == 2 ? bg : bv;

    if (seg == 3 && fl == 0) {
        // v written transposed, 8B-packed (4 consecutive m per lane)
#pragma unroll
        for (int im = 0; im < 8; im++)
#pragma unroll
            for (int jn = 0; jn < 4; jn++) {
                int nl = nl0 + wn * 64 + (jn >> 1) * 32 + (jn & 1) * 16 + ln15;
                float bsv = bias[nl];
                long mb = m0 + wm * 128 + (im >> 2) * 64 + (im & 3) * 16 + q4 * 4;
                unsigned short h0 = f2b(fw(acc[im][jn][0] + bsv));
                unsigned short h1 = f2b(fw(acc[im][jn][1] + bsv));
                unsigned short h2 = f2b(fw(acc[im][jn][2] + bsv));
                unsigned short h3 = f2b(fw(acc[im][jn][3] + bsv));
                uint2 pk;
                pk.x = (unsigned int)h0 | ((unsigned int)h1 << 16);
                pk.y = (unsigned int)h2 | ((unsigned int)h3 << 16);
                *(uint2*)(vT + (long)nl * T_LEN + mb) = pk;
            }
    } else {
#pragma unroll
        for (int im = 0; im < 8; im++)
#pragma unroll
            for (int jn = 0; jn < 4; jn++)
#pragma unroll
                for (int ii = 0; ii < 4; ii++) {
                    int dm = fl ? ln15 : q4 * 4 + ii;
                    int dn = fl ? q4 * 4 + ii : ln15;
                    long m = m0 + wm * 128 + (im >> 2) * 64 + (im & 3) * 16 + dm;
                    int nl = nl0 + wn * 64 + (jn >> 1) * 32 + (jn & 1) * 16 + dn;
                    float v = fw(acc[im][jn][ii] + bias[nl]);
                    if (seg == 1 || seg == 2) v = 1.0f / (1.0f + __expf(-v));
                    if (seg == 0)
                        qb[m * K_DIM + nl] = f2b(v);
                    else if (seg == 1)
                        kb[m * K_DIM + nl] = f2b(v);
                    else if (seg == 2)
                        gb[m * K_DIM + nl] = v;
                    else
                        vT[(long)nl * T_LEN + m] = f2b(v);
                }
    }
#undef STAGE_A
#undef STAGE_B
}

// ---------------------------------------------------------------------------
// Generic 128x128 bf16 GEMM (B^T input), fp32 out, global_load_lds staging.
__global__ __launch_bounds__(256) void gemm_f32_k(const unsigned short* __restrict__ A,
                                                  const unsigned short* __restrict__ BT,
                                                  const float* __restrict__ bias,
                                                  float* __restrict__ out,
                                                  int M, int N, int K,
                                                  const int* __restrict__ flagp) {
    __shared__ unsigned short As[128 * 32];
    __shared__ unsigned short Bs[128 * 32];
    int fl = *flagp;
    int tid = threadIdx.x;
    int lane = tid & 63;
    int w = tid >> 6;
    int ln15 = lane & 15, q4 = lane >> 4;
    int wm = w >> 1, wn = w & 1;
    long m0 = (long)blockIdx.x * 128, n0 = (long)blockIdx.y * 128;

    f32x4 acc[4][4] = {};

    for (int kt = 0; kt < K; kt += 32) {
        __syncthreads();
#pragma unroll
        for (int it = 0; it < 2; it++) {
            int chunk = it * 256 + tid;
            int row = chunk >> 2;
            int col = (chunk & 3) * 8;
            const unsigned short* ga = A + (m0 + row) * (long)K + kt + col;
            const unsigned short* gbp = BT + (n0 + row) * (long)K + kt + col;
            __builtin_amdgcn_global_load_lds((gptr1_t)(const void*)ga,
                                             (lptr3_t)(void*)(As + chunk * 8), 16, 0, 0);
            __builtin_amdgcn_global_load_lds((gptr1_t)(const void*)gbp,
                                             (lptr3_t)(void*)(Bs + chunk * 8), 16, 0, 0);
        }
        __syncthreads();
        bf16x8 a[4], b[4];
#pragma unroll
        for (int i = 0; i < 4; i++)
            a[i] = *(const bf16x8*)(As + (wm * 64 + 16 * i + ln15) * 32 + q4 * 8);
#pragma unroll
        for (int j = 0; j < 4; j++)
            b[j] = *(const bf16x8*)(Bs + (wn * 64 + 16 * j + ln15) * 32 + q4 * 8);
#pragma unroll
        for (int i = 0; i < 4; i++)
#pragma unroll
            for (int j = 0; j < 4; j++)
                acc[i][j] = __builtin_amdgcn_mfma_f32_16x16x32_bf16(a[i], b[j], acc[i][j], 0, 0, 0);
    }

#pragma unroll
    for (int i = 0; i < 4; i++)
#pragma unroll
        for (int j = 0; j < 4; j++)
#pragma unroll
            for (int ii = 0; ii < 4; ii++) {
                int dm = fl ? ln15 : q4 * 4 + ii;
                int dn = fl ? q4 * 4 + ii : ln15;
                long m = m0 + wm * 64 + 16 * i + dm;
                long n = n0 + wn * 64 + 16 * j + dn;
                out[m * N + n] = fw(acc[i][j][ii] + bias[n]);
            }
}

// ---------------------------------------------------------------------------
// Per (chunk, dim): cumulative gate products. In-place q->q*P, k->k/P; writes
// khatT[d][t] = k * Pend/P (transposed), pend[c][d].
__global__ __launch_bounds__(256) void cumprod_k(const float* __restrict__ g,
                                                 unsigned short* __restrict__ q,
                                                 unsigned short* __restrict__ k,
                                                 unsigned short* __restrict__ khatT,
                                                 float* __restrict__ pend) {
    int c = blockIdx.x;
    int d = blockIdx.y * 256 + threadIdx.x;
    long base = (long)c * CHUNK * K_DIM + d;
    float P = 1.0f;
    for (int s = 0; s < CHUNK; s++) P = fmaxf(P * g[base + (long)s * K_DIM], 1e-37f);
    pend[c * K_DIM + d] = P;
    float Pend = P;
    P = 1.0f;
    for (int s8 = 0; s8 < CHUNK; s8 += 8) {
        unsigned int packed[4];
#pragma unroll
        for (int u = 0; u < 8; u++) {
            int s = s8 + u;
            long idx = base + (long)s * K_DIM;
            P = fmaxf(P * g[idx], 1e-37f);
            float qv = fw(b2f(q[idx]) * P);
            q[idx] = f2b(qv);
            float kv = b2f(k[idx]);
            float kt = kv / P;
            kt = fmaxf(fminf(kt, 3e37f), -3e37f);
            k[idx] = f2b(kt);
            float ratio = Pend / P;  // in (0,1]
            unsigned short kh = f2b(fw(kv * ratio));
            if (u & 1)
                packed[u >> 1] |= ((unsigned int)kh) << 16;
            else
                packed[u >> 1] = kh;
        }
        uint4 pk;
        pk.x = packed[0]; pk.y = packed[1]; pk.z = packed[2]; pk.w = packed[3];
        *(uint4*)(khatT + (long)d * T_LEN + c * CHUNK + s8) = pk;
    }
}

// ---------------------------------------------------------------------------
// Sequential chunk scan over [c0, cn). fp32 state in Sio [K][V]; per chunk
// writes bf16 S-before into ST[(c-c0)] ([v][k], k contiguous).
__global__ __launch_bounds__(256) void scan_k(const unsigned short* __restrict__ khatT,
                                              const unsigned short* __restrict__ vT,
                                              const float* __restrict__ pend,
                                              unsigned short* __restrict__ ST,
                                              float* __restrict__ Sio,
                                              int c0, int cn,
                                              const int* __restrict__ flagp) {
    int fl = *flagp;
    int lane = threadIdx.x & 63, w = threadIdx.x >> 6;
    int ln15 = lane & 15, q4 = lane >> 4;
    int k0 = (blockIdx.x & 15) * 32 + (w & 1) * 16;
    int v0 = (blockIdx.x >> 4) * 32 + (w >> 1) * 16;
    f32x4 acc;
#pragma unroll
    for (int i = 0; i < 4; i++) {
        int dk = fl ? ln15 : q4 * 4 + i;
        int dv = fl ? q4 * 4 + i : ln15;
        acc[i] = Sio[(long)(k0 + dk) * V_DIM + v0 + dv];
    }
    for (int c = c0; c < cn; c++) {
        long cloc = c - c0;
        if (!fl) {
            uint2 pk;
            pk.x = (unsigned int)f2b(fw(acc[0])) | ((unsigned int)f2b(fw(acc[1])) << 16);
            pk.y = (unsigned int)f2b(fw(acc[2])) | ((unsigned int)f2b(fw(acc[3])) << 16);
            *(uint2*)(ST + (cloc * V_DIM + v0 + ln15) * K_DIM + k0 + q4 * 4) = pk;
            float4 pd = *(const float4*)(pend + c * K_DIM + k0 + q4 * 4);
            acc[0] *= pd.x; acc[1] *= pd.y; acc[2] *= pd.z; acc[3] *= pd.w;
        } else {
#pragma unroll
            for (int i = 0; i < 4; i++)
                ST[(cloc * V_DIM + v0 + q4 * 4 + i) * K_DIM + k0 + ln15] = f2b(fw(acc[i]));
            float pd = pend[c * K_DIM + k0 + ln15];
#pragma unroll
            for (int i = 0; i < 4; i++) acc[i] *= pd;
        }
#pragma unroll
        for (int s0 = 0; s0 < CHUNK; s0 += 32) {
            bf16x8 a = *(const bf16x8*)(khatT + (long)(k0 + ln15) * T_LEN + c * CHUNK + s0 + q4 * 8);
            bf16x8 b = *(const bf16x8*)(vT + (long)(v0 + ln15) * T_LEN + c * CHUNK + s0 + q4 * 8);
            acc = __builtin_amdgcn_mfma_f32_16x16x32_bf16(a, b, acc, 0, 0, 0);
        }
    }
#pragma unroll
    for (int i = 0; i < 4; i++) {
        int dk = fl ? ln15 : q4 * 4 + i;
        int dv = fl ? q4 * 4 + i : ln15;
        Sio[(long)(k0 + dk) * V_DIM + v0 + dv] = fw(acc[i]);
    }
}

// fp32 [K][V] state -> fp32 output copy
__global__ __launch_bounds__(256) void copy_state_k(const float* __restrict__ S,
                                                    float* __restrict__ out) {
    long i = (long)blockIdx.x * 1024 + threadIdx.x * 4;
    *(float4*)(out + i) = *(const float4*)(S + i);
}

// ---------------------------------------------------------------------------
// Per-chunk output: outs = Qs @ S_c + tril(Qs @ Ks^T) @ V_c. grid 2*CGROUP.
__global__ __launch_bounds__(256) void intra_k(const unsigned short* __restrict__ qs,
                                               const unsigned short* __restrict__ ks,
                                               const unsigned short* __restrict__ vT,
                                               const unsigned short* __restrict__ ST,
                                               unsigned short* __restrict__ outs,
                                               int c_base,
                                               const int* __restrict__ flagp) {
    __shared__ unsigned short Ab[64 * 72];
    int fl = *flagp;
    long cloc = blockIdx.x >> 1;
    int c = c_base + (int)cloc, h = blockIdx.x & 1;
    int lane = threadIdx.x & 63, w = threadIdx.x >> 6;
    int ln15 = lane & 15, q4 = lane >> 4;
    long t0 = (long)c * CHUNK;

    // Stage A: A = Qs @ Ks^T (64x64), causal mask (s <= t), bf16 into LDS
    {
        f32x4 accA[4] = {};
        for (int kk = 0; kk < K_DIM; kk += 32) {
            bf16x8 a = *(const bf16x8*)(qs + (t0 + 16 * w + ln15) * K_DIM + kk + q4 * 8);
#pragma unroll
            for (int j = 0; j < 4; j++) {
                bf16x8 b = *(const bf16x8*)(ks + (t0 + 16 * j + ln15) * K_DIM + kk + q4 * 8);
                accA[j] = __builtin_amdgcn_mfma_f32_16x16x32_bf16(a, b, accA[j], 0, 0, 0);
            }
        }
#pragma unroll
        for (int j = 0; j < 4; j++)
#pragma unroll
            for (int i = 0; i < 4; i++) {
                int dt = fl ? ln15 : q4 * 4 + i;
                int ds = fl ? q4 * 4 + i : ln15;
                int tl = 16 * w + dt;
                int s = 16 * j + ds;
                float av = (s <= tl) ? accA[j][i] : 0.0f;
                Ab[tl * 72 + s] = f2b(fw(av));
            }
    }
    __syncthreads();

    // Stage B: wave handles 64 v-cols. acc = Qs @ S^T + Ab @ V
    int v0 = h * 256 + w * 64;
    f32x4 acc[4][4] = {};
    for (int kk = 0; kk < K_DIM; kk += 32) {
        bf16x8 a[4], b[4];
#pragma unroll
        for (int i = 0; i < 4; i++)
            a[i] = *(const bf16x8*)(qs + (t0 + 16 * i + ln15) * K_DIM + kk + q4 * 8);
#pragma unroll
        for (int j = 0; j < 4; j++)
            b[j] = *(const bf16x8*)(ST + (cloc * V_DIM + v0 + 16 * j + ln15) * K_DIM + kk + q4 * 8);
#pragma unroll
        for (int i = 0; i < 4; i++)
#pragma unroll
            for (int j = 0; j < 4; j++)
                acc[i][j] = __builtin_amdgcn_mfma_f32_16x16x32_bf16(a[i], b[j], acc[i][j], 0, 0, 0);
    }
#pragma unroll
    for (int s0 = 0; s0 < CHUNK; s0 += 32) {
        bf16x8 a[4], b[4];
#pragma unroll
        for (int i = 0; i < 4; i++)
            a[i] = *(const bf16x8*)(Ab + (16 * i + ln15) * 72 + s0 + q4 * 8);
#pragma unroll
        for (int j = 0; j < 4; j++)
            b[j] = *(const bf16x8*)(vT + (long)(v0 + 16 * j + ln15) * T_LEN + t0 + s0 + q4 * 8);
#pragma unroll
        for (int i = 0; i < 4; i++)
#pragma unroll
            for (int j = 0; j < 4; j++)
                acc[i][j] = __builtin_amdgcn_mfma_f32_16x16x32_bf16(a[i], b[j], acc[i][j], 0, 0, 0);
    }
#pragma unroll
    for (int i = 0; i < 4; i++)
#pragma unroll
        for (int j = 0; j < 4; j++)
#pragma unroll
            for (int ii = 0; ii < 4; ii++) {
                int dt = fl ? ln15 : q4 * 4 + ii;
                int dv = fl ? q4 * 4 + ii : ln15;
                outs[(t0 + 16 * i + dt) * V_DIM + v0 + 16 * j + dv] = f2b(fw(acc[i][j][ii]));
            }
}

// ---------------------------------------------------------------------------
extern "C" void kernel_launch(void* const* d_in, const int* in_sizes, int n_in,
                              void* d_out, int out_size, void* d_ws, size_t ws_size,
                              hipStream_t stream) {
    const float* hs = (const float*)d_in[0];
    const float* Wq = (const float*)d_in[1];
    const float* bq = (const float*)d_in[2];
    const float* Wk = (const float*)d_in[3];
    const float* bk = (const float*)d_in[4];
    const float* Wv = (const float*)d_in[5];
    const float* bv = (const float*)d_in[6];
    const float* Wg = (const float*)d_in[7];
    const float* bg = (const float*)d_in[8];
    const float* Wo = (const float*)d_in[9];
    const float* bo = (const float*)d_in[10];

    float* out = (float*)d_out;  // fp32 output

    // Workspace layout, peak 93 MB (<= 116 MB demonstrated safe in r1/r2).
    char* ws = (char*)d_ws;
    const size_t MB = 1024 * 1024;
    unsigned short* WT = (unsigned short*)(ws + 0 * MB);      // 8 MB: q|k|g|v transposed [2048][2048]
    unsigned short* WoT = (unsigned short*)(ws + 8 * MB);     // 2 MB
    unsigned short* qb = (unsigned short*)(ws + 10 * MB);     // 8 MB
    unsigned short* kb = (unsigned short*)(ws + 18 * MB);     // 8 MB
    unsigned short* vTb = (unsigned short*)(ws + 26 * MB);    // 8 MB (written by proj gemm)
    float* gb = (float*)(ws + 34 * MB);                       // 16 MB fp32
    unsigned short* outsb = (unsigned short*)(ws + 34 * MB);  // 8 MB, reuses gb after cumprod
    unsigned short* khatT = (unsigned short*)(ws + 50 * MB);  // 8 MB
    float* pend = (float*)(ws + 58 * MB);                     // 256 KB
    int* flags = (int*)(ws + 58 * MB + 256 * 1024);           // [0] layout flag
    float* Scarry = (float*)(ws + 59 * MB);                   // 1 MB fp32 [K][V]
    unsigned short* STb = (unsigned short*)(ws + 60 * MB);    // 32 MB (CGROUP chunks)
    unsigned short* hsb = (unsigned short*)(ws + 60 * MB);    // 32 MB, dead before scan
    float* fsspare = (float*)(ws + 92 * MB);                  // 1 MB -> peak 93 MB
    (void)ws_size; (void)in_sizes; (void)n_in;

    float* finalst =
        ((long)out_size >= (long)T_LEN * O_DIM + (long)K_DIM * V_DIM)
            ? out + (long)T_LEN * O_DIM
            : fsspare;

    dim3 b256(256);
    hipMemsetAsync(flags, 0, 16, stream);
    probe_k<<<dim3(1), dim3(64), 0, stream>>>(flags);
    // canonicalize fp32 inputs to bf16
    conv2bf_k<<<dim3(8192), b256, 0, stream>>>(hs, hsb, (long)T_LEN * H_DIM);
    // weight transposes into the stacked WT (q|k|g|v) and WoT
    transpose_k<1><<<dim3(H_DIM / 32, K_DIM / 32), b256, 0, stream>>>(Wq, WT + 0 * 512 * H_DIM, H_DIM, K_DIM);
    transpose_k<1><<<dim3(H_DIM / 32, K_DIM / 32), b256, 0, stream>>>(Wk, WT + 1 * 512 * H_DIM, H_DIM, K_DIM);
    transpose_k<1><<<dim3(H_DIM / 32, K_DIM / 32), b256, 0, stream>>>(Wg, WT + 2 * 512 * H_DIM, H_DIM, K_DIM);
    transpose_k<1><<<dim3(H_DIM / 32, V_DIM / 32), b256, 0, stream>>>(Wv, WT + 3 * 512 * H_DIM, H_DIM, V_DIM);
    transpose_k<1><<<dim3(V_DIM / 32, O_DIM / 32), b256, 0, stream>>>(Wo, WoT, V_DIM, O_DIM);
    // fused q/k/g/v projection (v written transposed), 256x256 8-phase
    proj_gemm256_k<<<dim3(T_LEN / 256, 8), dim3(512), 0, stream>>>(
        hsb, WT, bq, bk, bg, bv, qb, kb, gb, vTb, flags);
    // gate cumulative products
    cumprod_k<<<dim3(NCHUNK, K_DIM / 256), b256, 0, stream>>>(gb, qb, kb, khatT, pend);
    // 2-pass chunk scan + intra
    hipMemsetAsync(Scarry, 0, (size_t)K_DIM * V_DIM * 4, stream);
    scan_k<<<dim3(256), b256, 0, stream>>>(khatT, vTb, pend, STb, Scarry, 0, CGROUP, flags);
    intra_k<<<dim3(2 * CGROUP), b256, 0, stream>>>(qb, kb, vTb, STb, outsb, 0, flags);
    scan_k<<<dim3(256), b256, 0, stream>>>(khatT, vTb, pend, STb, Scarry, CGROUP, NCHUNK, flags);
    intra_k<<<dim3(2 * CGROUP), b256, 0, stream>>>(qb, kb, vTb, STb, outsb, CGROUP, flags);
    copy_state_k<<<dim3((K_DIM * V_DIM) / 1024), b256, 0, stream>>>(Scarry, finalst);
    // final projection -> fp32 d_out
    gemm_f32_k<<<dim3(T_LEN / 128, O_DIM / 128), b256, 0, stream>>>(
        outsb, WoT, bo, out, T_LEN, O_DIM, V_DIM, flags);
}

// Round 2
// 389.714 us; speedup vs baseline: 1.2371x; 1.1694x over previous
//
#include <hip/hip_runtime.h>

// Problem dims
#define T_LEN 8192
#define H_DIM 2048
#define K_DIM 512
#define V_DIM 512
#define O_DIM 2048
#define CHUNK 64
#define NCHUNK 128   // T_LEN / CHUNK

typedef short bf16x8 __attribute__((ext_vector_type(8)));
typedef float f32x4 __attribute__((ext_vector_type(4)));

typedef const __attribute__((address_space(1))) void* gptr1_t;
typedef __attribute__((address_space(3))) void* lptr3_t;

__device__ __forceinline__ float b2f(unsigned short u) {
    unsigned int i = ((unsigned int)u) << 16;
    float f;
    __builtin_memcpy(&f, &i, 4);
    return f;
}
__device__ __forceinline__ unsigned short f2b(float f) {
    unsigned int i;
    __builtin_memcpy(&i, &f, 4);
    unsigned int r = (i + 0x7FFFu + ((i >> 16) & 1u)) >> 16;  // RNE
    return (unsigned short)r;
}
// NaN/inf firewall
__device__ __forceinline__ float fw(float v) {
    return fminf(fmaxf(v, -1e30f), 1e30f);
}

#define BARX() asm volatile("s_barrier" ::: "memory")

// ---------------------------------------------------------------------------
// Runtime C/D-layout probe for mfma_f32_16x16x32_bf16 (vs our load convention).
__global__ __launch_bounds__(64) void probe_k(int* __restrict__ flag) {
    __shared__ unsigned short As[16 * 32];
    __shared__ unsigned short Bs[16 * 32];
    int tid = threadIdx.x;
    for (int idx = tid; idx < 512; idx += 64) {
        int r = idx >> 5, c = idx & 31;
        float av = (c == 0) ? (float)(r + 1) : (c == 1 ? 1.0f : 0.0f);
        float bv = (c == 0) ? 1.0f : (c == 1 ? (float)(1024 * (r + 1)) : 0.0f);
        As[r * 32 + c] = f2b(av);
        Bs[r * 32 + c] = f2b(bv);
    }
    __syncthreads();
    int ln15 = tid & 15, q4 = (tid & 63) >> 4;
    bf16x8 a = *(const bf16x8*)(As + ln15 * 32 + q4 * 8);
    bf16x8 b = *(const bf16x8*)(Bs + ln15 * 32 + q4 * 8);
    f32x4 acc = {0.f, 0.f, 0.f, 0.f};
    acc = __builtin_amdgcn_mfma_f32_16x16x32_bf16(a, b, acc, 0, 0, 0);
    bool h0 = true, h1 = true;
#pragma unroll
    for (int i = 0; i < 4; i++) {
        float e0 = (float)((q4 * 4 + i + 1) + 1024 * (ln15 + 1));
        float e1 = (float)((ln15 + 1) + 1024 * (q4 * 4 + i + 1));
        h0 = h0 && (acc[i] == e0);
        h1 = h1 && (acc[i] == e1);
    }
    unsigned long long b0 = __ballot(h0 ? 1 : 0);
    unsigned long long b1 = __ballot(h1 ? 1 : 0);
    if (tid == 0) *flag = (b0 == ~0ull) ? 0 : ((b1 == ~0ull) ? 1 : 0);
}

// ---------------------------------------------------------------------------
// Merged prep: fp32->bf16 conv of hidden_state (blocks 0..8191) + 5 weight
// transposes to bf16 (blocks 8192..13311, 1024 tiles per matrix).
__global__ __launch_bounds__(256) void prep_k(const float* __restrict__ hs,
                                              unsigned short* __restrict__ hsb,
                                              const float* __restrict__ Wq,
                                              const float* __restrict__ Wk,
                                              const float* __restrict__ Wg,
                                              const float* __restrict__ Wv,
                                              const float* __restrict__ Wo,
                                              unsigned short* __restrict__ WT,
                                              unsigned short* __restrict__ WoT) {
    __shared__ unsigned short tile[32][33];
    long bid = blockIdx.x;
    int tid = threadIdx.x;
    if (bid < 8192) {
        long i = (bid * 256 + tid) * 8;
        unsigned int wd[4];
#pragma unroll
        for (int u = 0; u < 4; u++) {
            unsigned short lo = f2b(hs[i + 2 * u]);
            unsigned short hi = f2b(hs[i + 2 * u + 1]);
            wd[u] = (unsigned int)lo | ((unsigned int)hi << 16);
        }
        uint4 pk; pk.x = wd[0]; pk.y = wd[1]; pk.z = wd[2]; pk.w = wd[3];
        *(uint4*)(hsb + i) = pk;
        return;
    }
    int t = (int)(bid - 8192);
    int mat = t >> 10, tl = t & 1023;
    const float* in; unsigned short* outp; int R, C, br, bc;
    if (mat < 4) {
        in = mat == 0 ? Wq : mat == 1 ? Wk : mat == 2 ? Wg : Wv;
        outp = WT + (long)mat * 512 * H_DIM;
        R = H_DIM; C = 512; br = tl >> 4; bc = tl & 15;
    } else {
        in = Wo; outp = WoT; R = V_DIM; C = O_DIM; br = tl & 15; bc = tl >> 4;
    }
    int tc = tid & 31, tr = tid >> 5;
#pragma unroll
    for (int i = 0; i < 4; i++) {
        int r = tr + 8 * i;
        long idx = (long)(br * 32 + r) * C + bc * 32 + tc;
        tile[r][tc] = f2b(in[idx]);
    }
    __syncthreads();
#pragma unroll
    for (int i = 0; i < 4; i++) {
        int r = tr + 8 * i;
        outp[(long)(bc * 32 + r) * R + br * 32 + tc] = tile[tc][r];
    }
}

// ---------------------------------------------------------------------------
// Fused projection GEMM, 256x256 8-phase (T2+T3+T4+T5). Barriers are asm
// s_barrier with memory clobber; NO lgkmcnt(0)/sched_barrier pins — compiler
// emits fine-grained lgkmcnt so slot-1 ds_reads overlap slot-0 MFMAs.
// Hazard audit: every ds_read result is consumed by an in-phase MFMA, so all
// reads of a buffer slot drain >=2 barriers before that slot is re-staged.
__global__ __launch_bounds__(512, 2) void proj_gemm256_k(const unsigned short* __restrict__ A,
                                                         const unsigned short* __restrict__ WT,
                                                         const float* __restrict__ bq,
                                                         const float* __restrict__ bk,
                                                         const float* __restrict__ bg,
                                                         const float* __restrict__ bv,
                                                         unsigned short* __restrict__ qb,
                                                         unsigned short* __restrict__ kb,
                                                         float* __restrict__ gb,
                                                         unsigned short* __restrict__ vT,
                                                         const int* __restrict__ flagp) {
    __shared__ unsigned short As[2][256 * 64];  // 64 KiB
    __shared__ unsigned short Bs[2][256 * 64];  // 64 KiB
    int fl = *flagp;
    int tid = threadIdx.x;
    int lane = tid & 63;
    int ln15 = lane & 15, q4 = lane >> 4;
    int w = tid >> 6;
    int wm = w >> 2, wn = w & 3;  // 2 x 4 wave grid; wave owns 128 rows x 64 cols
    long m0 = (long)blockIdx.x * 256, n0 = (long)blockIdx.y * 256;

    // staging geometry (per thread, 2 loads per half-tile); T2 source pre-swizzle
    int idx0 = tid, idx1 = 512 + tid;
    int r0_ = idx0 >> 3, r1_ = idx1 >> 3;
    int c80 = (idx0 & 7) ^ (r0_ & 7);
    int c81 = (idx1 & 7) ^ (r1_ & 7);
    int trA0 = ((r0_ >> 6) & 1) * 128 + (r0_ & 63);
    int trA1 = ((r1_ >> 6) & 1) * 128 + (r1_ & 63);
    int tcB0 = ((r0_ >> 5) & 3) * 64 + (r0_ & 31);
    int tcB1 = ((r1_ >> 5) & 3) * 64 + (r1_ & 31);
    const unsigned short* gA0 = A + (m0 + trA0) * (long)H_DIM + c80 * 8;
    const unsigned short* gA1 = A + (m0 + trA1) * (long)H_DIM + c81 * 8;
    const unsigned short* gB0 = WT + (n0 + tcB0) * (long)H_DIM + c80 * 8;
    const unsigned short* gB1 = WT + (n0 + tcB1) * (long)H_DIM + c81 * 8;
    int ld0 = idx0 * 8, ld1 = idx1 * 8;

#define STAGE_A(buf, half, ks)                                                              \
    do {                                                                                    \
        __builtin_amdgcn_global_load_lds(                                                   \
            (gptr1_t)(const void*)(gA0 + (long)(half) * 64 * H_DIM + (ks)),                 \
            (lptr3_t)(void*)(&As[buf][(half) * 8192 + ld0]), 16, 0, 0);                     \
        __builtin_amdgcn_global_load_lds(                                                   \
            (gptr1_t)(const void*)(gA1 + (long)(half) * 64 * H_DIM + (ks)),                 \
            (lptr3_t)(void*)(&As[buf][(half) * 8192 + ld1]), 16, 0, 0);                     \
    } while (0)
#define STAGE_B(buf, half, ks)                                                              \
    do {                                                                                    \
        __builtin_amdgcn_global_load_lds(                                                   \
            (gptr1_t)(const void*)(gB0 + (long)(half) * 32 * H_DIM + (ks)),                 \
            (lptr3_t)(void*)(&Bs[buf][(half) * 8192 + ld0]), 16, 0, 0);                     \
        __builtin_amdgcn_global_load_lds(                                                   \
            (gptr1_t)(const void*)(gB1 + (long)(half) * 32 * H_DIM + (ks)),                 \
            (lptr3_t)(void*)(&Bs[buf][(half) * 8192 + ld1]), 16, 0, 0);                     \
    } while (0)

    auto LDA = [&](int buf, int im, int s) -> bf16x8 {
        int row = (im >> 2) * 128 + wm * 64 + (im & 3) * 16 + ln15;
        int cb = (s * 64 + q4 * 16) ^ ((row & 7) << 4);
        return *(const bf16x8*)((const unsigned short*)As[buf] + row * 64 + (cb >> 1));
    };
    auto LDB = [&](int buf, int jn, int s) -> bf16x8 {
        int row = (jn >> 1) * 128 + wn * 32 + (jn & 1) * 16 + ln15;
        int cb = (s * 64 + q4 * 16) ^ ((row & 7) << 4);
        return *(const bf16x8*)((const unsigned short*)Bs[buf] + row * 64 + (cb >> 1));
    };

    f32x4 acc[8][4] = {};

    // prologue: tile0 full -> buf0, tile1 lo-halves -> buf1
    STAGE_A(0, 0, 0);
    STAGE_B(0, 0, 0);
    STAGE_B(0, 1, 0);
    STAGE_A(0, 1, 0);
    STAGE_A(1, 0, 64);
    STAGE_B(1, 0, 64);
    asm volatile("s_waitcnt vmcnt(4)" ::: "memory");
    BARX();

    int cur = 0;
    for (int kt = 0; kt < H_DIM; kt += 64, cur ^= 1) {
        int k1 = (kt + 64) & (H_DIM - 1);
        int k2 = (kt + 128) & (H_DIM - 1);
        bf16x8 af[4][2], blo[2][2], bhi[2][2];

        // phase r0: quadrant (m-lo, n-lo)
#pragma unroll
        for (int i = 0; i < 4; i++) { af[i][0] = LDA(cur, i, 0); af[i][1] = LDA(cur, i, 1); }
#pragma unroll
        for (int j = 0; j < 2; j++) { blo[j][0] = LDB(cur, j, 0); blo[j][1] = LDB(cur, j, 1); }
        STAGE_B(cur ^ 1, 1, k1);
        BARX();
        __builtin_amdgcn_s_setprio(1);
#pragma unroll
        for (int i = 0; i < 4; i++)
#pragma unroll
            for (int j = 0; j < 2; j++) {
                acc[i][j] = __builtin_amdgcn_mfma_f32_16x16x32_bf16(af[i][0], blo[j][0], acc[i][j], 0, 0, 0);
                acc[i][j] = __builtin_amdgcn_mfma_f32_16x16x32_bf16(af[i][1], blo[j][1], acc[i][j], 0, 0, 0);
            }
        __builtin_amdgcn_s_setprio(0);
        BARX();

        // phase r1: quadrant (m-lo, n-hi)
#pragma unroll
        for (int j = 0; j < 2; j++) { bhi[j][0] = LDB(cur, 2 + j, 0); bhi[j][1] = LDB(cur, 2 + j, 1); }
        STAGE_A(cur ^ 1, 1, k1);
        BARX();
        __builtin_amdgcn_s_setprio(1);
#pragma unroll
        for (int i = 0; i < 4; i++)
#pragma unroll
            for (int j = 0; j < 2; j++) {
                acc[i][2 + j] = __builtin_amdgcn_mfma_f32_16x16x32_bf16(af[i][0], bhi[j][0], acc[i][2 + j], 0, 0, 0);
                acc[i][2 + j] = __builtin_amdgcn_mfma_f32_16x16x32_bf16(af[i][1], bhi[j][1], acc[i][2 + j], 0, 0, 0);
            }
        __builtin_amdgcn_s_setprio(0);
        BARX();

        // phase r2: quadrant (m-hi, n-hi)
#pragma unroll
        for (int i = 0; i < 4; i++) { af[i][0] = LDA(cur, 4 + i, 0); af[i][1] = LDA(cur, 4 + i, 1); }
        STAGE_A(cur, 0, k2);  // A-lo(cur): last read in r0, >=2 barriers ago
        BARX();
        __builtin_amdgcn_s_setprio(1);
#pragma unroll
        for (int i = 0; i < 4; i++)
#pragma unroll
            for (int j = 0; j < 2; j++) {
                acc[4 + i][2 + j] = __builtin_amdgcn_mfma_f32_16x16x32_bf16(af[i][0], bhi[j][0], acc[4 + i][2 + j], 0, 0, 0);
                acc[4 + i][2 + j] = __builtin_amdgcn_mfma_f32_16x16x32_bf16(af[i][1], bhi[j][1], acc[4 + i][2 + j], 0, 0, 0);
            }
        __builtin_amdgcn_s_setprio(0);
        BARX();

        // phase r3: quadrant (m-hi, n-lo), regs only
        STAGE_B(cur, 0, k2);  // B-lo(cur): last read in r0
        __builtin_amdgcn_s_setprio(1);
#pragma unroll
        for (int i = 0; i < 4; i++)
#pragma unroll
            for (int j = 0; j < 2; j++) {
                acc[4 + i][j] = __builtin_amdgcn_mfma_f32_16x16x32_bf16(af[i][0], blo[j][0], acc[4 + i][j], 0, 0, 0);
                acc[4 + i][j] = __builtin_amdgcn_mfma_f32_16x16x32_bf16(af[i][1], blo[j][1], acc[4 + i][j], 0, 0, 0);
            }
        __builtin_amdgcn_s_setprio(0);
        asm volatile("s_waitcnt vmcnt(4)" ::: "memory");  // tile t+1 landed, t+2-lo in flight
        BARX();
    }

    // epilogue
    int seg = (int)(n0 >> 9);        // 0=q 1=k 2=g 3=v
    int nl0 = (int)(n0 & 511);
    const float* bias = seg == 0 ? bq : seg == 1 ? bk : seg == 2 ? bg : bv;

    if (seg == 3 && fl == 0) {
#pragma unroll
        for (int im = 0; im < 8; im++)
#pragma unroll
            for (int jn = 0; jn < 4; jn++) {
                int nl = nl0 + wn * 64 + (jn >> 1) * 32 + (jn & 1) * 16 + ln15;
                float bsv = bias[nl];
                long mb = m0 + wm * 128 + (im >> 2) * 64 + (im & 3) * 16 + q4 * 4;
                unsigned short h0 = f2b(fw(acc[im][jn][0] + bsv));
                unsigned short h1 = f2b(fw(acc[im][jn][1] + bsv));
                unsigned short h2 = f2b(fw(acc[im][jn][2] + bsv));
                unsigned short h3 = f2b(fw(acc[im][jn][3] + bsv));
                uint2 pk;
                pk.x = (unsigned int)h0 | ((unsigned int)h1 << 16);
                pk.y = (unsigned int)h2 | ((unsigned int)h3 << 16);
                *(uint2*)(vT + (long)nl * T_LEN + mb) = pk;
            }
    } else {
#pragma unroll
        for (int im = 0; im < 8; im++)
#pragma unroll
            for (int jn = 0; jn < 4; jn++)
#pragma unroll
                for (int ii = 0; ii < 4; ii++) {
                    int dm = fl ? ln15 : q4 * 4 + ii;
                    int dn = fl ? q4 * 4 + ii : ln15;
                    long m = m0 + wm * 128 + (im >> 2) * 64 + (im & 3) * 16 + dm;
                    int nl = nl0 + wn * 64 + (jn >> 1) * 32 + (jn & 1) * 16 + dn;
                    float v = fw(acc[im][jn][ii] + bias[nl]);
                    if (seg == 1 || seg == 2) v = 1.0f / (1.0f + __expf(-v));
                    if (seg == 0)
                        qb[m * K_DIM + nl] = f2b(v);
                    else if (seg == 1)
                        kb[m * K_DIM + nl] = f2b(v);
                    else if (seg == 2)
                        gb[m * K_DIM + nl] = v;
                    else
                        vT[(long)nl * T_LEN + m] = f2b(v);
                }
    }
#undef STAGE_A
#undef STAGE_B
}

// ---------------------------------------------------------------------------
// Final projection GEMM, same 256x256 8-phase structure. A=[T][KT] bf16,
// BT=[N][KT] bf16, fp32 out + bias. KT runtime (512 here), power of 2.
__global__ __launch_bounds__(512, 2) void gemm256_k(const unsigned short* __restrict__ A,
                                                    const unsigned short* __restrict__ BT,
                                                    const float* __restrict__ bias,
                                                    float* __restrict__ out,
                                                    int N, int KT,
                                                    const int* __restrict__ flagp) {
    __shared__ unsigned short As[2][256 * 64];
    __shared__ unsigned short Bs[2][256 * 64];
    int fl = *flagp;
    int tid = threadIdx.x;
    int lane = tid & 63;
    int ln15 = lane & 15, q4 = lane >> 4;
    int w = tid >> 6;
    int wm = w >> 2, wn = w & 3;
    long m0 = (long)blockIdx.x * 256, n0 = (long)blockIdx.y * 256;

    int idx0 = tid, idx1 = 512 + tid;
    int r0_ = idx0 >> 3, r1_ = idx1 >> 3;
    int c80 = (idx0 & 7) ^ (r0_ & 7);
    int c81 = (idx1 & 7) ^ (r1_ & 7);
    int trA0 = ((r0_ >> 6) & 1) * 128 + (r0_ & 63);
    int trA1 = ((r1_ >> 6) & 1) * 128 + (r1_ & 63);
    int tcB0 = ((r0_ >> 5) & 3) * 64 + (r0_ & 31);
    int tcB1 = ((r1_ >> 5) & 3) * 64 + (r1_ & 31);
    const unsigned short* gA0 = A + (m0 + trA0) * (long)KT + c80 * 8;
    const unsigned short* gA1 = A + (m0 + trA1) * (long)KT + c81 * 8;
    const unsigned short* gB0 = BT + (n0 + tcB0) * (long)KT + c80 * 8;
    const unsigned short* gB1 = BT + (n0 + tcB1) * (long)KT + c81 * 8;
    int ld0 = idx0 * 8, ld1 = idx1 * 8;

#define STAGE_A(buf, half, ks)                                                              \
    do {                                                                                    \
        __builtin_amdgcn_global_load_lds(                                                   \
            (gptr1_t)(const void*)(gA0 + (long)(half) * 64 * KT + (ks)),                    \
            (lptr3_t)(void*)(&As[buf][(half) * 8192 + ld0]), 16, 0, 0);                     \
        __builtin_amdgcn_global_load_lds(                                                   \
            (gptr1_t)(const void*)(gA1 + (long)(half) * 64 * KT + (ks)),                    \
            (lptr3_t)(void*)(&As[buf][(half) * 8192 + ld1]), 16, 0, 0);                     \
    } while (0)
#define STAGE_B(buf, half, ks)                                                              \
    do {                                                                                    \
        __builtin_amdgcn_global_load_lds(                                                   \
            (gptr1_t)(const void*)(gB0 + (long)(half) * 32 * KT + (ks)),                    \
            (lptr3_t)(void*)(&Bs[buf][(half) * 8192 + ld0]), 16, 0, 0);                     \
        __builtin_amdgcn_global_load_lds(                                                   \
            (gptr1_t)(const void*)(gB1 + (long)(half) * 32 * KT + (ks)),                    \
            (lptr3_t)(void*)(&Bs[buf][(half) * 8192 + ld1]), 16, 0, 0);                     \
    } while (0)

    auto LDA = [&](int buf, int im, int s) -> bf16x8 {
        int row = (im >> 2) * 128 + wm * 64 + (im & 3) * 16 + ln15;
        int cb = (s * 64 + q4 * 16) ^ ((row & 7) << 4);
        return *(const bf16x8*)((const unsigned short*)As[buf] + row * 64 + (cb >> 1));
    };
    auto LDB = [&](int buf, int jn, int s) -> bf16x8 {
        int row = (jn >> 1) * 128 + wn * 32 + (jn & 1) * 16 + ln15;
        int cb = (s * 64 + q4 * 16) ^ ((row & 7) << 4);
        return *(const bf16x8*)((const unsigned short*)Bs[buf] + row * 64 + (cb >> 1));
    };

    f32x4 acc[8][4] = {};

    STAGE_A(0, 0, 0);
    STAGE_B(0, 0, 0);
    STAGE_B(0, 1, 0);
    STAGE_A(0, 1, 0);
    STAGE_A(1, 0, 64);
    STAGE_B(1, 0, 64);
    asm volatile("s_waitcnt vmcnt(4)" ::: "memory");
    BARX();

    int cur = 0;
    for (int kt = 0; kt < KT; kt += 64, cur ^= 1) {
        int k1 = (kt + 64) & (KT - 1);
        int k2 = (kt + 128) & (KT - 1);
        bf16x8 af[4][2], blo[2][2], bhi[2][2];

#pragma unroll
        for (int i = 0; i < 4; i++) { af[i][0] = LDA(cur, i, 0); af[i][1] = LDA(cur, i, 1); }
#pragma unroll
        for (int j = 0; j < 2; j++) { blo[j][0] = LDB(cur, j, 0); blo[j][1] = LDB(cur, j, 1); }
        STAGE_B(cur ^ 1, 1, k1);
        BARX();
        __builtin_amdgcn_s_setprio(1);
#pragma unroll
        for (int i = 0; i < 4; i++)
#pragma unroll
            for (int j = 0; j < 2; j++) {
                acc[i][j] = __builtin_amdgcn_mfma_f32_16x16x32_bf16(af[i][0], blo[j][0], acc[i][j], 0, 0, 0);
                acc[i][j] = __builtin_amdgcn_mfma_f32_16x16x32_bf16(af[i][1], blo[j][1], acc[i][j], 0, 0, 0);
            }
        __builtin_amdgcn_s_setprio(0);
        BARX();

#pragma unroll
        for (int j = 0; j < 2; j++) { bhi[j][0] = LDB(cur, 2 + j, 0); bhi[j][1] = LDB(cur, 2 + j, 1); }
        STAGE_A(cur ^ 1, 1, k1);
        BARX();
        __builtin_amdgcn_s_setprio(1);
#pragma unroll
        for (int i = 0; i < 4; i++)
#pragma unroll
            for (int j = 0; j < 2; j++) {
                acc[i][2 + j] = __builtin_amdgcn_mfma_f32_16x16x32_bf16(af[i][0], bhi[j][0], acc[i][2 + j], 0, 0, 0);
                acc[i][2 + j] = __builtin_amdgcn_mfma_f32_16x16x32_bf16(af[i][1], bhi[j][1], acc[i][2 + j], 0, 0, 0);
            }
        __builtin_amdgcn_s_setprio(0);
        BARX();

#pragma unroll
        for (int i = 0; i < 4; i++) { af[i][0] = LDA(cur, 4 + i, 0); af[i][1] = LDA(cur, 4 + i, 1); }
        STAGE_A(cur, 0, k2);
        BARX();
        __builtin_amdgcn_s_setprio(1);
#pragma unroll
        for (int i = 0; i < 4; i++)
#pragma unroll
            for (int j = 0; j < 2; j++) {
                acc[4 + i][2 + j] = __builtin_amdgcn_mfma_f32_16x16x32_bf16(af[i][0], bhi[j][0], acc[4 + i][2 + j], 0, 0, 0);
                acc[4 + i][2 + j] = __builtin_amdgcn_mfma_f32_16x16x32_bf16(af[i][1], bhi[j][1], acc[4 + i][2 + j], 0, 0, 0);
            }
        __builtin_amdgcn_s_setprio(0);
        BARX();

        STAGE_B(cur, 0, k2);
        __builtin_amdgcn_s_setprio(1);
#pragma unroll
        for (int i = 0; i < 4; i++)
#pragma unroll
            for (int j = 0; j < 2; j++) {
                acc[4 + i][j] = __builtin_amdgcn_mfma_f32_16x16x32_bf16(af[i][0], blo[j][0], acc[4 + i][j], 0, 0, 0);
                acc[4 + i][j] = __builtin_amdgcn_mfma_f32_16x16x32_bf16(af[i][1], blo[j][1], acc[4 + i][j], 0, 0, 0);
            }
        __builtin_amdgcn_s_setprio(0);
        asm volatile("s_waitcnt vmcnt(4)" ::: "memory");
        BARX();
    }

#pragma unroll
    for (int im = 0; im < 8; im++)
#pragma unroll
        for (int jn = 0; jn < 4; jn++)
#pragma unroll
            for (int ii = 0; ii < 4; ii++) {
                int dm = fl ? ln15 : q4 * 4 + ii;
                int dn = fl ? q4 * 4 + ii : ln15;
                long m = m0 + wm * 128 + (im >> 2) * 64 + (im & 3) * 16 + dm;
                long n = n0 + wn * 64 + (jn >> 1) * 32 + (jn & 1) * 16 + dn;
                out[m * N + n] = fw(acc[im][jn][ii] + bias[n]);
            }
#undef STAGE_A
#undef STAGE_B
}

// ---------------------------------------------------------------------------
// Per (chunk, dim): cumulative gate products. g cached in 64 regs (one read
// pass). In-place q->q*P, k->k/P; writes khatT[d][t] (transposed), pend[c][d].
__global__ __launch_bounds__(256) void cumprod_k(const float* __restrict__ g,
                                                 unsigned short* __restrict__ q,
                                                 unsigned short* __restrict__ k,
                                                 unsigned short* __restrict__ khatT,
                                                 float* __restrict__ pend) {
    int c = blockIdx.x;
    int d = blockIdx.y * 256 + threadIdx.x;
    long base = (long)c * CHUNK * K_DIM + d;
    float gv[CHUNK];
#pragma unroll
    for (int s = 0; s < CHUNK; s++) gv[s] = g[base + (long)s * K_DIM];
    float P = 1.0f;
#pragma unroll
    for (int s = 0; s < CHUNK; s++) { P = fmaxf(P * gv[s], 1e-37f); gv[s] = P; }  // gv = cumP
    pend[c * K_DIM + d] = P;
    float Pend = P;
#pragma unroll
    for (int s8 = 0; s8 < CHUNK; s8 += 8) {
        unsigned int packed[4];
#pragma unroll
        for (int u = 0; u < 8; u++) {
            int s = s8 + u;
            long idx = base + (long)s * K_DIM;
            float Pc = gv[s];
            float qv = fw(b2f(q[idx]) * Pc);
            q[idx] = f2b(qv);
            float kv = b2f(k[idx]);
            float kt = kv / Pc;
            kt = fmaxf(fminf(kt, 3e37f), -3e37f);
            k[idx] = f2b(kt);
            float ratio = Pend / Pc;  // in (0,1]
            unsigned short kh = f2b(fw(kv * ratio));
            if (u & 1)
                packed[u >> 1] |= ((unsigned int)kh) << 16;
            else
                packed[u >> 1] = kh;
        }
        uint4 pk;
        pk.x = packed[0]; pk.y = packed[1]; pk.z = packed[2]; pk.w = packed[3];
        *(uint4*)(khatT + (long)d * T_LEN + c * CHUNK + s8) = pk;
    }
}

// ---------------------------------------------------------------------------
// Single sequential chunk scan over all NCHUNK chunks, acc starts at 0.
// 4-deep register prefetch of khatT/vT fragments and decay factors.
// Per chunk writes bf16 S-before into ST[c] ([v][k], k contiguous); final
// fp32 state -> fstate.
__global__ __launch_bounds__(256) void scan_k(const unsigned short* __restrict__ khatT,
                                              const unsigned short* __restrict__ vT,
                                              const float* __restrict__ pend,
                                              unsigned short* __restrict__ ST,
                                              float* __restrict__ fstate,
                                              const int* __restrict__ flagp) {
    int fl = *flagp;
    int lane = threadIdx.x & 63, w = threadIdx.x >> 6;
    int ln15 = lane & 15, q4 = lane >> 4;
    int k0 = (blockIdx.x & 15) * 32 + (w & 1) * 16;
    int v0 = (blockIdx.x >> 4) * 32 + (w >> 1) * 16;
    f32x4 acc = {0.f, 0.f, 0.f, 0.f};
    const unsigned short* kb_ = khatT + (long)(k0 + ln15) * T_LEN + q4 * 8;
    const unsigned short* vb_ = vT + (long)(v0 + ln15) * T_LEN + q4 * 8;

    bf16x8 kf0[2], vf0[2], kf1[2], vf1[2], kf2[2], vf2[2], kf3[2], vf3[2];
    float4 pdv[4];
    float pds[4];

#define LOADSET(s, c)                                                        \
    do {                                                                     \
        long off_ = (long)(c) * CHUNK;                                       \
        kf##s[0] = *(const bf16x8*)(kb_ + off_);                             \
        kf##s[1] = *(const bf16x8*)(kb_ + off_ + 32);                        \
        vf##s[0] = *(const bf16x8*)(vb_ + off_);                             \
        vf##s[1] = *(const bf16x8*)(vb_ + off_ + 32);                        \
        if (!fl)                                                             \
            pdv[s] = *(const float4*)(pend + (c) * K_DIM + k0 + q4 * 4);     \
        else                                                                 \
            pds[s] = pend[(c) * K_DIM + k0 + ln15];                          \
    } while (0)

    LOADSET(0, 0); LOADSET(1, 1); LOADSET(2, 2); LOADSET(3, 3);

#define STEP(s, c)                                                                             \
    do {                                                                                       \
        if (!fl) {                                                                             \
            uint2 pk_;                                                                         \
            pk_.x = (unsigned int)f2b(fw(acc[0])) | ((unsigned int)f2b(fw(acc[1])) << 16);     \
            pk_.y = (unsigned int)f2b(fw(acc[2])) | ((unsigned int)f2b(fw(acc[3])) << 16);     \
            *(uint2*)(ST + ((long)(c) * V_DIM + v0 + ln15) * K_DIM + k0 + q4 * 4) = pk_;       \
            acc[0] *= pdv[s].x; acc[1] *= pdv[s].y; acc[2] *= pdv[s].z; acc[3] *= pdv[s].w;    \
        } else {                                                                               \
            ST[((long)(c) * V_DIM + v0 + q4 * 4 + 0) * K_DIM + k0 + ln15] = f2b(fw(acc[0]));   \
            ST[((long)(c) * V_DIM + v0 + q4 * 4 + 1) * K_DIM + k0 + ln15] = f2b(fw(acc[1]));   \
            ST[((long)(c) * V_DIM + v0 + q4 * 4 + 2) * K_DIM + k0 + ln15] = f2b(fw(acc[2]));   \
            ST[((long)(c) * V_DIM + v0 + q4 * 4 + 3) * K_DIM + k0 + ln15] = f2b(fw(acc[3]));   \
            acc[0] *= pds[s]; acc[1] *= pds[s]; acc[2] *= pds[s]; acc[3] *= pds[s];            \
        }                                                                                      \
        acc = __builtin_amdgcn_mfma_f32_16x16x32_bf16(kf##s[0], vf##s[0], acc, 0, 0, 0);       \
        acc = __builtin_amdgcn_mfma_f32_16x16x32_bf16(kf##s[1], vf##s[1], acc, 0, 0, 0);       \
        int cp_ = (c) + 4;                                                                     \
        if (cp_ > NCHUNK - 1) cp_ = NCHUNK - 1;                                                \
        LOADSET(s, cp_);                                                                       \
    } while (0)

    for (int c = 0; c < NCHUNK; c += 4) {
        STEP(0, c);
        STEP(1, c + 1);
        STEP(2, c + 2);
        STEP(3, c + 3);
    }
#undef STEP
#undef LOADSET

#pragma unroll
    for (int i = 0; i < 4; i++) {
        int dk = fl ? ln15 : q4 * 4 + i;
        int dv = fl ? q4 * 4 + i : ln15;
        fstate[(long)(k0 + dk) * V_DIM + v0 + dv] = fw(acc[i]);
    }
}

// ---------------------------------------------------------------------------
// Per-chunk output: outs = Qs @ S_c + tril(Qs @ Ks^T) @ V_c. grid 2*NCHUNK.
__global__ __launch_bounds__(256) void intra_k(const unsigned short* __restrict__ qs,
                                               const unsigned short* __restrict__ ks,
                                               const unsigned short* __restrict__ vT,
                                               const unsigned short* __restrict__ ST,
                                               unsigned short* __restrict__ outs,
                                               const int* __restrict__ flagp) {
    __shared__ unsigned short Ab[64 * 72];
    int fl = *flagp;
    long cloc = blockIdx.x >> 1;
    int c = (int)cloc, h = blockIdx.x & 1;
    int lane = threadIdx.x & 63, w = threadIdx.x >> 6;
    int ln15 = lane & 15, q4 = lane >> 4;
    long t0 = (long)c * CHUNK;

    // Stage A: A = Qs @ Ks^T (64x64), causal mask (s <= t), bf16 into LDS
    {
        f32x4 accA[4] = {};
        for (int kk = 0; kk < K_DIM; kk += 32) {
            bf16x8 a = *(const bf16x8*)(qs + (t0 + 16 * w + ln15) * K_DIM + kk + q4 * 8);
#pragma unroll
            for (int j = 0; j < 4; j++) {
                bf16x8 b = *(const bf16x8*)(ks + (t0 + 16 * j + ln15) * K_DIM + kk + q4 * 8);
                accA[j] = __builtin_amdgcn_mfma_f32_16x16x32_bf16(a, b, accA[j], 0, 0, 0);
            }
        }
#pragma unroll
        for (int j = 0; j < 4; j++)
#pragma unroll
            for (int i = 0; i < 4; i++) {
                int dt = fl ? ln15 : q4 * 4 + i;
                int ds = fl ? q4 * 4 + i : ln15;
                int tl = 16 * w + dt;
                int s = 16 * j + ds;
                float av = (s <= tl) ? accA[j][i] : 0.0f;
                Ab[tl * 72 + s] = f2b(fw(av));
            }
    }
    __syncthreads();

    // Stage B: wave handles 64 v-cols. acc = Qs @ S^T + Ab @ V
    int v0 = h * 256 + w * 64;
    f32x4 acc[4][4] = {};
    for (int kk = 0; kk < K_DIM; kk += 32) {
        bf16x8 a[4], b[4];
#pragma unroll
        for (int i = 0; i < 4; i++)
            a[i] = *(const bf16x8*)(qs + (t0 + 16 * i + ln15) * K_DIM + kk + q4 * 8);
#pragma unroll
        for (int j = 0; j < 4; j++)
            b[j] = *(const bf16x8*)(ST + (cloc * V_DIM + v0 + 16 * j + ln15) * K_DIM + kk + q4 * 8);
#pragma unroll
        for (int i = 0; i < 4; i++)
#pragma unroll
            for (int j = 0; j < 4; j++)
                acc[i][j] = __builtin_amdgcn_mfma_f32_16x16x32_bf16(a[i], b[j], acc[i][j], 0, 0, 0);
    }
#pragma unroll
    for (int s0 = 0; s0 < CHUNK; s0 += 32) {
        bf16x8 a[4], b[4];
#pragma unroll
        for (int i = 0; i < 4; i++)
            a[i] = *(const bf16x8*)(Ab + (16 * i + ln15) * 72 + s0 + q4 * 8);
#pragma unroll
        for (int j = 0; j < 4; j++)
            b[j] = *(const bf16x8*)(vT + (long)(v0 + 16 * j + ln15) * T_LEN + t0 + s0 + q4 * 8);
#pragma unroll
        for (int i = 0; i < 4; i++)
#pragma unroll
            for (int j = 0; j < 4; j++)
                acc[i][j] = __builtin_amdgcn_mfma_f32_16x16x32_bf16(a[i], b[j], acc[i][j], 0, 0, 0);
    }
#pragma unroll
    for (int i = 0; i < 4; i++)
#pragma unroll
        for (int j = 0; j < 4; j++)
#pragma unroll
            for (int ii = 0; ii < 4; ii++) {
                int dt = fl ? ln15 : q4 * 4 + ii;
                int dv = fl ? q4 * 4 + ii : ln15;
                outs[(t0 + 16 * i + dt) * V_DIM + v0 + 16 * j + dv] = f2b(fw(acc[i][j][ii]));
            }
}

// ---------------------------------------------------------------------------
extern "C" void kernel_launch(void* const* d_in, const int* in_sizes, int n_in,
                              void* d_out, int out_size, void* d_ws, size_t ws_size,
                              hipStream_t stream) {
    const float* hs = (const float*)d_in[0];
    const float* Wq = (const float*)d_in[1];
    const float* bq = (const float*)d_in[2];
    const float* Wk = (const float*)d_in[3];
    const float* bk = (const float*)d_in[4];
    const float* Wv = (const float*)d_in[5];
    const float* bv = (const float*)d_in[6];
    const float* Wg = (const float*)d_in[7];
    const float* bg = (const float*)d_in[8];
    const float* Wo = (const float*)d_in[9];
    const float* bo = (const float*)d_in[10];

    float* out = (float*)d_out;  // fp32 output

    // Workspace layout, peak 109 MB (<= 116 MB demonstrated safe).
    // Liveness: WT [prep,proj] / outsb [intra,gemm] share 0..8.
    //           gb [proj,cumprod] + hsb [prep,proj] are both dead before scan,
    //           so STb (64 MB, [scan,intra]) reuses 44..108.
    char* ws = (char*)d_ws;
    const size_t MB = 1024 * 1024;
    unsigned short* WT = (unsigned short*)(ws + 0 * MB);      // 8 MB: q|k|g|v transposed
    unsigned short* outsb = (unsigned short*)(ws + 0 * MB);   // 8 MB (after proj)
    unsigned short* WoT = (unsigned short*)(ws + 8 * MB);     // 2 MB
    unsigned short* qb = (unsigned short*)(ws + 10 * MB);     // 8 MB
    unsigned short* kb = (unsigned short*)(ws + 18 * MB);     // 8 MB
    unsigned short* vTb = (unsigned short*)(ws + 26 * MB);    // 8 MB
    unsigned short* khatT = (unsigned short*)(ws + 34 * MB);  // 8 MB
    float* pend = (float*)(ws + 42 * MB);                     // 256 KB
    int* flags = (int*)(ws + 42 * MB + 256 * 1024);           // [0] layout flag
    float* gb = (float*)(ws + 44 * MB);                       // 16 MB fp32 (dead after cumprod)
    unsigned short* STb = (unsigned short*)(ws + 44 * MB);    // 64 MB (all 128 chunks)
    unsigned short* hsb = (unsigned short*)(ws + 60 * MB);    // 32 MB (dead after proj)
    float* fsspare = (float*)(ws + 108 * MB);                 // 1 MB -> peak 109 MB
    (void)ws_size; (void)in_sizes; (void)n_in;

    float* finalst =
        ((long)out_size >= (long)T_LEN * O_DIM + (long)K_DIM * V_DIM)
            ? out + (long)T_LEN * O_DIM
            : fsspare;

    dim3 b256(256);
    hipMemsetAsync(flags, 0, 16, stream);
    probe_k<<<dim3(1), dim3(64), 0, stream>>>(flags);
    // conv + all weight transposes, one launch
    prep_k<<<dim3(8192 + 5 * 1024), b256, 0, stream>>>(hs, hsb, Wq, Wk, Wg, Wv, Wo, WT, WoT);
    // fused q/k/g/v projection (v written transposed), 256x256 8-phase
    proj_gemm256_k<<<dim3(T_LEN / 256, 8), dim3(512), 0, stream>>>(
        hsb, WT, bq, bk, bg, bv, qb, kb, gb, vTb, flags);
    // gate cumulative products
    cumprod_k<<<dim3(NCHUNK, K_DIM / 256), b256, 0, stream>>>(gb, qb, kb, khatT, pend);
    // single-pass chunk scan (writes all 128 chunk states + final state)
    scan_k<<<dim3(256), b256, 0, stream>>>(khatT, vTb, pend, STb, finalst, flags);
    // intra-chunk outputs, full GPU in one launch
    intra_k<<<dim3(2 * NCHUNK), b256, 0, stream>>>(qb, kb, vTb, STb, outsb, flags);
    // final projection -> fp32 d_out, 256x256 8-phase
    gemm256_k<<<dim3(T_LEN / 256, O_DIM / 256), dim3(512), 0, stream>>>(
        outsb, WoT, bo, out, O_DIM, V_DIM, flags);
}